// Round 2
// baseline (16403.389 us; speedup 1.0000x reference)
//
#include <hip/hip_runtime.h>

// Fully fused OT Sinkhorn loss, MI355X.
// Key facts: (1) images are independent -> 1 WG (1024 thr) per image runs all
// 100 iterations with __syncthreads only (kills 200 x ~12us dispatch latency).
// (2) K is separable AND banded: 11x11 window (tap 6+ contributes <1e-8 rel
// even vs eps-inflated v~1e12). Per-point taps live in REGISTERS.
// (3) scatter/gather LDS bank = (ix0+k)&31 -> one-time counting sort of points
// by ix0 + stride-16 wave assignment spreads each wave's lanes across banks.

#define N_IMG   8
#define N_PTS   1024
#define OUT_D   128
#define N_CELLS (OUT_D * OUT_D)
#define WIN     11
#define RT      5
#define EPS     1e-16f
#define INV_N   (1.0f / 1024.0f)
#define N_ITERS 100

__device__ __forceinline__ float blk_sum(float v, volatile float* red)
{
#pragma unroll
    for (int o = 32; o; o >>= 1) v += __shfl_xor(v, o, 64);
    int wave = threadIdx.x >> 6, lane = threadIdx.x & 63;
    if (lane == 0) red[wave] = v;
    __syncthreads();
    if (threadIdx.x < 64) {
        float t = (lane < 16) ? red[lane] : 0.0f;
#pragma unroll
        for (int o = 8; o; o >>= 1) t += __shfl_xor(t, o, 64);
        if (lane == 0) red[0] = t;
    }
    __syncthreads();
    float r = red[0];
    __syncthreads();            // red reusable by next call
    return r;
}

__global__ __launch_bounds__(1024) void ot_fused(
    const float* __restrict__ nd, const float* __restrict__ und,
    const float* __restrict__ pts, float* __restrict__ parts)
{
    __shared__ float V[N_CELLS];      // 64KB: S, then v in place
    __shared__ int   perm[N_PTS];     // 4KB
    __shared__ int   hist[128];
    __shared__ float red[64];

    const int img = blockIdx.x;
    const int tid = threadIdx.x;
    const float* ndi = nd + img * N_CELLS;

    // ---- one-time: sort points by ix0, stride-16 wave assignment ----------
    float x = pts[(img * N_PTS + tid) * 2 + 0];
    int nxr = (int)floorf((x - 2.0f) * 0.25f + 0.5f);
    int ixr = min(max(nxr - RT, 0), OUT_D - WIN);
    if (tid < 128) hist[tid] = 0;
    __syncthreads();
    atomicAdd(&hist[ixr], 1);
    __syncthreads();
    if (tid == 0) {                   // serial 128-bin exclusive prefix (once)
        int acc = 0;
        for (int i = 0; i < 128; ++i) { int h = hist[i]; hist[i] = acc; acc += h; }
    }
    __syncthreads();
    int pos = atomicAdd(&hist[ixr], 1);
    perm[pos] = tid;
    __syncthreads();
    const int myp = perm[((tid & 63) << 4) | (tid >> 6)];  // lane*16 + wave

    // ---- per-point static data in registers -------------------------------
    x       = pts[(img * N_PTS + myp) * 2 + 0];
    float y = pts[(img * N_PTS + myp) * 2 + 1];
    int nx = (int)floorf((x - 2.0f) * 0.25f + 0.5f);
    int ny = (int)floorf((y - 2.0f) * 0.25f + 0.5f);
    const int ix0 = min(max(nx - RT, 0), OUT_D - WIN);
    const int iy0 = min(max(ny - RT, 0), OUT_D - WIN);
    const float xx = x * x, yy = y * y;
    float kx[WIN], ky[WIN];
#pragma unroll
    for (int k = 0; k < WIN; ++k) {   // mimic reference's expanded x^2-2xc+c^2
        float cx = (float)(4 * (ix0 + k) + 2);
        kx[k] = __expf(-((xx - 2.0f * x * cx) + cx * cx) * 0.1f);
        float cy = (float)(4 * (iy0 + k) + 2);
        ky[k] = __expf(-((yy - 2.0f * y * cy) + cy * cy) * 0.1f);
    }
    float u = INV_N;
    const int sbase = iy0 * OUT_D + ix0;

    // ---- Sinkhorn main loop ----------------------------------------------
    for (int it = 0; it < N_ITERS; ++it) {
        __syncthreads();              // prev gather readers done with V
#pragma unroll
        for (int r = 0; r < 4; ++r)   // zero S: 16 floats/thread
            ((float4*)V)[r * 1024 + tid] = make_float4(0.f, 0.f, 0.f, 0.f);
        __syncthreads();

        // scatter: S += u * ky (outer) kx   (121 ds_add_f32, imm offsets)
#pragma unroll
        for (int j = 0; j < WIN; ++j) {
            float c = u * ky[j];
            float* row = V + sbase + j * OUT_D;
#pragma unroll
            for (int k = 0; k < WIN; ++k)
                atomicAdd(&row[k], c * kx[k]);
        }
        __syncthreads();

        // v = b / (S + eps)   (b streamed from L1/L2, same 64KB each iter)
#pragma unroll
        for (int r = 0; r < 16; ++r) {
            int c = r * 1024 + tid;
            V[c] = ndi[c] / (V[c] + EPS);
        }
        __syncthreads();

        // gather: t = sum_j ky_j * sum_k kx_k * v
        float t = 0.0f;
#pragma unroll
        for (int j = 0; j < WIN; ++j) {
            const float* row = V + sbase + j * OUT_D;
            float rs = 0.0f;
#pragma unroll
            for (int k = 0; k < WIN; ++k) rs = fmaf(kx[k], row[k], rs);
            t = fmaf(ky[j], rs, t);
        }
        u = INV_N / (t + EPS);
    }
    __syncthreads();                  // V = final v

    // ---- epilogue ---------------------------------------------------------
    const float* sdi = und + img * N_CELLS;
    float sc = 0.f, T = 0.f, ot = 0.f;
#pragma unroll
    for (int r = 0; r < 16; ++r) {
        int c = r * 1024 + tid;
        float beta = 10.0f * logf(V[c] + EPS);
        float s = sdi[c];
        sc += s;
        T  = fmaf(s, beta, T);
        ot = fmaf(ndi[c], beta, ot);
    }
    sc = blk_sum(sc, red);
    T  = blk_sum(T,  red);
    ot = blk_sum(ot, red);
    float denom = sc * sc + 1e-8f;
    float c1 = sc / denom, c2 = T / denom;

    float loss = 0.f;
#pragma unroll
    for (int r = 0; r < 16; ++r) {
        int c = r * 1024 + tid;
        float beta = 10.0f * logf(V[c] + EPS);
        loss = fmaf(sdi[c], fmaf(c1, beta, -c2), loss);
    }
    loss = blk_sum(loss, red);

    // wd = sum_n u_n * sum_window (dy+dx)*Ky*Kx*v
    float wd = 0.f;
#pragma unroll
    for (int j = 0; j < WIN; ++j) {
        float cy = (float)(4 * (iy0 + j) + 2);
        float dy = (yy - 2.0f * y * cy) + cy * cy;
        const float* row = V + sbase + j * OUT_D;
        float skv = 0.f, sdkv = 0.f;
#pragma unroll
        for (int k = 0; k < WIN; ++k) {
            float cx = (float)(4 * (ix0 + k) + 2);
            float dx = (xx - 2.0f * x * cx) + cx * cx;
            float kv = kx[k] * row[k];
            skv += kv;
            sdkv = fmaf(dx, kv, sdkv);
        }
        wd = fmaf(ky[j], fmaf(dy, skv, sdkv), wd);
    }
    wd *= u;
    wd = blk_sum(wd, red);

    if (tid == 0) {
        parts[img * 3 + 0] = loss;
        parts[img * 3 + 1] = wd;
        parts[img * 3 + 2] = ot;
    }
}

__global__ void ot_sum(const float* __restrict__ parts, float* __restrict__ out)
{
    int t = threadIdx.x;
    if (t < 3) {
        float s = 0.f;
        for (int i = 0; i < N_IMG; ++i) s += parts[i * 3 + t];
        out[t] = s;
    }
}

// ---------------------------------------------------------------- launch ---
extern "C" void kernel_launch(void* const* d_in, const int* in_sizes, int n_in,
                              void* d_out, int out_size, void* d_ws, size_t ws_size,
                              hipStream_t stream)
{
    const float* nd  = (const float*)d_in[0];   // normed_density  [8][16384]
    const float* und = (const float*)d_in[1];   // unnormed_density[8][16384]
    const float* pts = (const float*)d_in[2];   // points          [8][1024][2]
    float* parts = (float*)d_ws;                // 24 floats

    ot_fused<<<N_IMG, 1024, 0, stream>>>(nd, und, pts, parts);
    ot_sum<<<1, 64, 0, stream>>>(parts, (float*)d_out);
}

// Round 3
// 4608.309 us; speedup vs baseline: 3.5595x; 3.5595x over previous
//
#include <hip/hip_runtime.h>

// Fused OT Sinkhorn loss, MI355X — round 3: ATOMIC-FREE phase A.
// Round-2 lesson: 124K LDS f32 atomics/iter on ONE CU's LDS pipe cost ~3cy
// per LANE (per-lane RMW serialization) -> 164us/iter. Fix: ownership.
// Each of 16 waves owns an 8-row slab of S in REGISTERS (lane l owns cols
// {l, l+64} x 8 rows). A one-time CSR (per-slab entry list, each entry =
// header + zero-padded slab-aligned 8x bf16 ky profile, 16B) makes the
// scatter a broadcast-read + FMA loop: no atomics, no bank conflicts.
// v lives in LDS as bf16 (32KB) so total LDS = 152KB fits in 160KB.

#define N_IMG   8
#define N_PTS   1024
#define OUT_D   128
#define N_CELLS (OUT_D * OUT_D)
#define WIN     11
#define RT      5
#define MAXE    288
#define EPS     1e-16f
#define INV_N   (1.0f / 1024.0f)
#define N_ITERS 100

typedef unsigned short ushort_t;
typedef unsigned int   uint_t;

__device__ __forceinline__ ushort_t f2bf(float f) {   // RNE f32->bf16
    uint_t b = __float_as_uint(f);
    b += 0x7FFFu + ((b >> 16) & 1u);
    return (ushort_t)(b >> 16);
}
__device__ __forceinline__ float bf2f(ushort_t h) {
    return __uint_as_float(((uint_t)h) << 16);
}

__device__ __forceinline__ float blk_sum(float v, volatile float* red)
{
#pragma unroll
    for (int o = 32; o; o >>= 1) v += __shfl_xor(v, o, 64);
    int wave = threadIdx.x >> 6, lane = threadIdx.x & 63;
    if (lane == 0) red[wave] = v;
    __syncthreads();
    if (threadIdx.x < 64) {
        float t = (lane < 16) ? red[lane] : 0.0f;
#pragma unroll
        for (int o = 8; o; o >>= 1) t += __shfl_xor(t, o, 64);
        if (lane == 0) red[0] = t;
    }
    __syncthreads();
    float r = red[0];
    __syncthreads();
    return r;
}

__global__ __launch_bounds__(1024) void ot_fused(
    const float* __restrict__ nd, const float* __restrict__ und,
    const float* __restrict__ pts, float* __restrict__ parts)
{
    __shared__ ushort_t Vh[N_CELLS];        // 32KB  v as bf16
    __shared__ uint4    KYS[16 * MAXE];     // 72KB  8x bf16 ky slab-profiles
    __shared__ uint_t   HDR[16 * MAXE];     // 18KB  point id | ix0
    __shared__ ushort_t Kxh[N_PTS * WIN];   // 22KB  bf16 kx taps
    __shared__ float    su[N_PTS];          // 4KB   published u
    __shared__ int      cnt[16];
    __shared__ float    red[64];

    const int img  = blockIdx.x;
    const int tid  = threadIdx.x;
    const int w    = tid >> 6;              // wave = slab owner (rows 8w..8w+7)
    const int l    = tid & 63;              // lane owns cols l and l+64
    const float* ndi = nd + img * N_CELLS;

    // ---- zero CSR region --------------------------------------------------
    for (int i = tid; i < 16 * MAXE; i += 1024)
        KYS[i] = make_uint4(0u, 0u, 0u, 0u);
    if (tid < 16) cnt[tid] = 0;
    __syncthreads();

    // ---- per-point static data (registers) + CSR build --------------------
    const float x  = pts[(img * N_PTS + tid) * 2 + 0];
    const float y  = pts[(img * N_PTS + tid) * 2 + 1];
    const int nx = (int)floorf((x - 2.0f) * 0.25f + 0.5f);
    const int ny = (int)floorf((y - 2.0f) * 0.25f + 0.5f);
    const int ix0 = min(max(nx - RT, 0), OUT_D - WIN);
    const int iy0 = min(max(ny - RT, 0), OUT_D - WIN);
    const float xx = x * x, yy = y * y;
    float kxr[WIN], kyr[WIN];
#pragma unroll
    for (int k = 0; k < WIN; ++k) {         // mimic reference's x^2-2xc+c^2
        float cx = (float)(4 * (ix0 + k) + 2);
        kxr[k] = __expf(-((xx - 2.0f * x * cx) + cx * cx) * 0.1f);
        float cy = (float)(4 * (iy0 + k) + 2);
        kyr[k] = __expf(-((yy - 2.0f * y * cy) + cy * cy) * 0.1f);
        Kxh[tid * WIN + k] = f2bf(kxr[k]);
    }
    float u = INV_N;
    su[tid] = INV_N;

    const int s_lo = iy0 >> 3, s_hi = (iy0 + WIN - 1) >> 3;   // <= 15
    for (int s = s_lo; s <= s_hi; ++s) {
        int e = atomicAdd(&cnt[s], 1);      // int LDS atomic, once — fine
        if (e < MAXE) {
            HDR[s * MAXE + e] = (uint_t)tid | ((uint_t)ix0 << 10);
            int rbase = s * 8 - iy0;        // j = rbase + r
            ushort_t* dst = (ushort_t*)&KYS[s * MAXE + e];
#pragma unroll
            for (int j = 0; j < WIN; ++j) {
                int r = j - rbase;
                if (0 <= r && r < 8) dst[r] = f2bf(kyr[j]);
            }
        }
    }
    __syncthreads();

    const int ne = cnt[w];
    const uint_t* hb = &HDR[w * MAXE];
    const uint4*  tb = &KYS[w * MAXE];
    const int sbase = iy0 * OUT_D + ix0;

    // ---- Sinkhorn main loop ----------------------------------------------
    for (int it = 0; it < N_ITERS; ++it) {
        __syncthreads();                    // su fresh; prev gather done w/ Vh

        // phase A: slab-ownership scatter into registers (no atomics)
        float accA[8] = {0,0,0,0,0,0,0,0};
        float accB[8] = {0,0,0,0,0,0,0,0};
#pragma unroll 2
        for (int e = 0; e < ne; ++e) {
            uint_t h = hb[e];               // broadcast
            int p    = h & 1023;
            int ixe  = (h >> 10) & 127;
            uint4 tw = tb[e];               // broadcast ds_read_b128
            float uv = su[p];               // broadcast
            int d0 = l - ixe;               // col l tap index
            int d1 = d0 + 64;               // col l+64 tap index
            bool i0 = (unsigned)d0 < (unsigned)WIN;
            bool i1 = (unsigned)d1 < (unsigned)WIN;
            int d = i0 ? d0 : (i1 ? d1 : 0);
            float kxv = bf2f(Kxh[p * WIN + d]);
            float cA = i0 ? uv * kxv : 0.0f;
            float cB = i1 ? uv * kxv : 0.0f;
#pragma unroll
            for (int r = 0; r < 8; ++r) {
                uint_t dwv = (r < 2) ? tw.x : (r < 4) ? tw.y : (r < 6) ? tw.z : tw.w;
                float kyv = __uint_as_float((r & 1) ? (dwv & 0xFFFF0000u) : (dwv << 16));
                accA[r] = fmaf(cA, kyv, accA[r]);
                accB[r] = fmaf(cB, kyv, accB[r]);
            }
        }
        // v = b/(S+eps) for owned cells, store bf16
#pragma unroll
        for (int r = 0; r < 8; ++r) {
            int cell = (w * 8 + r) * OUT_D + l;
            float b0 = ndi[cell], b1 = ndi[cell + 64];
            Vh[cell]      = f2bf(b0 / (accA[r] + EPS));
            Vh[cell + 64] = f2bf(b1 / (accB[r] + EPS));
        }
        __syncthreads();

        // phase B: per-point gather (register taps, bf16 v)
        float t_ = 0.0f;
#pragma unroll
        for (int j = 0; j < WIN; ++j) {
            const ushort_t* row = &Vh[sbase + j * OUT_D];
            float rs = 0.0f;
#pragma unroll
            for (int k = 0; k < WIN; ++k) rs = fmaf(kxr[k], bf2f(row[k]), rs);
            t_ = fmaf(kyr[j], rs, t_);
        }
        u = INV_N / (t_ + EPS);
        su[tid] = u;
    }
    __syncthreads();                        // Vh = final v

    // ---- epilogue ---------------------------------------------------------
    const float* sdi = und + img * N_CELLS;
    float sc = 0.f, T = 0.f, ot = 0.f;
#pragma unroll
    for (int r = 0; r < 16; ++r) {
        int c = r * 1024 + tid;
        float beta = 10.0f * logf(bf2f(Vh[c]) + EPS);
        float s = sdi[c];
        sc += s;
        T  = fmaf(s, beta, T);
        ot = fmaf(ndi[c], beta, ot);
    }
    sc = blk_sum(sc, red);
    T  = blk_sum(T,  red);
    ot = blk_sum(ot, red);
    float denom = sc * sc + 1e-8f;
    float c1 = sc / denom, c2 = T / denom;

    float loss = 0.f;
#pragma unroll
    for (int r = 0; r < 16; ++r) {
        int c = r * 1024 + tid;
        float beta = 10.0f * logf(bf2f(Vh[c]) + EPS);
        loss = fmaf(sdi[c], fmaf(c1, beta, -c2), loss);
    }
    loss = blk_sum(loss, red);

    // wd = u_n * sum_window (dy+dx)*Ky*Kx*v   (exact f32 taps from registers)
    float wd = 0.f;
#pragma unroll
    for (int j = 0; j < WIN; ++j) {
        float cy = (float)(4 * (iy0 + j) + 2);
        float dy = (yy - 2.0f * y * cy) + cy * cy;
        const ushort_t* row = &Vh[sbase + j * OUT_D];
        float skv = 0.f, sdkv = 0.f;
#pragma unroll
        for (int k = 0; k < WIN; ++k) {
            float cx = (float)(4 * (ix0 + k) + 2);
            float dx = (xx - 2.0f * x * cx) + cx * cx;
            float kv = kxr[k] * bf2f(row[k]);
            skv += kv;
            sdkv = fmaf(dx, kv, sdkv);
        }
        wd = fmaf(kyr[j], fmaf(dy, skv, sdkv), wd);
    }
    wd *= u;
    wd = blk_sum(wd, red);

    if (tid == 0) {
        parts[img * 3 + 0] = loss;
        parts[img * 3 + 1] = wd;
        parts[img * 3 + 2] = ot;
    }
}

__global__ void ot_sum(const float* __restrict__ parts, float* __restrict__ out)
{
    int t = threadIdx.x;
    if (t < 3) {
        float s = 0.f;
        for (int i = 0; i < N_IMG; ++i) s += parts[i * 3 + t];
        out[t] = s;
    }
}

// ---------------------------------------------------------------- launch ---
extern "C" void kernel_launch(void* const* d_in, const int* in_sizes, int n_in,
                              void* d_out, int out_size, void* d_ws, size_t ws_size,
                              hipStream_t stream)
{
    const float* nd  = (const float*)d_in[0];   // normed_density  [8][16384]
    const float* und = (const float*)d_in[1];   // unnormed_density[8][16384]
    const float* pts = (const float*)d_in[2];   // points          [8][1024][2]
    float* parts = (float*)d_ws;                // 24 floats

    ot_fused<<<N_IMG, 1024, 0, stream>>>(nd, und, pts, parts);
    ot_sum<<<1, 64, 0, stream>>>(parts, (float*)d_out);
}

// Round 4
// 2160.792 us; speedup vs baseline: 7.5914x; 2.1327x over previous
//
#include <hip/hip_runtime.h>

// Fused OT Sinkhorn, MI355X — round 4: phase A as a per-CELL gather.
// Round-3 lesson: slab-scatter phase A had ~6% useful-lane density (30 VALU
// inst per ~60 useful MACs) -> VALU-issue-bound at 23us/half-step on 1 CU.
// Fix: prebuilt per-cell contributor lists. Pair = u32 [ bf16(ky*kx) <<16 | pid ].
// Static across iters (only u changes). Phase A per pair: 1 coalesced stream
// load + 1 ds_read su[pid] + 2 and + 1 fma, accumulate in REGISTER (lane owns
// cell). Cells counting-sorted by list length -> per-wave-chunk equal lengths,
// ~5% padding. Builder is one-time and atomic-light: 2D histogram + per-row
// prefix tables give every pair a deterministic list position.

#define N_IMG   8
#define N_PTS   1024
#define OUT_D   128
#define N_CELLS (OUT_D * OUT_D)
#define WIN     11
#define RT      5
#define EPS     1e-16f
#define INV_N   (1.0f / 1024.0f)
#define N_ITERS 100
#define STREAM_CAP 524288          // u32 words per image (2MB); worst case <191K

typedef unsigned int   uint_t;
typedef unsigned short ushort_t;

__device__ __forceinline__ ushort_t f2bf(float f) {    // RNE f32->bf16
    uint_t b = __float_as_uint(f);
    b += 0x7FFFu + ((b >> 16) & 1u);
    return (ushort_t)(b >> 16);
}

// ---------------------------------------------------------------- builder --
// One WG per image. Deterministic pair positions:
//   cell list order = (iy0 asc, ix0 asc, pid asc).
//   idx = sum_{rows before iy0} rowcnt + (same-row ix0' < ix0) + rank(pid).
__global__ __launch_bounds__(1024) void ot_build(
    const float* __restrict__ pts, uint_t* __restrict__ stream,
    uint_t* __restrict__ cellofg, uint_t* __restrict__ cbaseg,
    uint_t* __restrict__ cleng)
{
    __shared__ uint_t   SH[N_CELLS];        // 64KB: H counts -> len|slot<<16
    __shared__ ushort_t P[128 * 129];       // 33KB: row prefix of H
    __shared__ ushort_t cell0tab[N_PTS];    // 2KB
    __shared__ ushort_t cellof_l[N_CELLS];  // 32KB: slot -> cell
    __shared__ uint_t   bins[1025];         // 4KB
    __shared__ uint_t   cbase_l[257];       // 1KB

    const int img = blockIdx.x, tid = threadIdx.x;

    for (int i = tid; i < N_CELLS; i += 1024) SH[i] = 0;
    for (int i = tid; i < 1025; i += 1024) bins[i] = 0;
    __syncthreads();

    // point data (thread = point)
    const float x = pts[(img * N_PTS + tid) * 2 + 0];
    const float y = pts[(img * N_PTS + tid) * 2 + 1];
    const int nx = (int)floorf((x - 2.f) * 0.25f + 0.5f);
    const int ny = (int)floorf((y - 2.f) * 0.25f + 0.5f);
    const int ix0 = min(max(nx - RT, 0), OUT_D - WIN);
    const int iy0 = min(max(ny - RT, 0), OUT_D - WIN);
    const float xx = x * x, yy = y * y;
    float kx[WIN], ky[WIN];
#pragma unroll
    for (int k = 0; k < WIN; ++k) {         // mimic reference's x^2-2xc+c^2
        float cx = (float)(4 * (ix0 + k) + 2);
        kx[k] = __expf(-((xx - 2.f * x * cx) + cx * cx) * 0.1f);
        float cy = (float)(4 * (iy0 + k) + 2);
        ky[k] = __expf(-((yy - 2.f * y * cy) + cy * cy) * 0.1f);
    }
    const int cell0 = (iy0 << 7) | ix0;
    cell0tab[tid] = (ushort_t)cell0;
    atomicAdd(&SH[cell0], 1u);
    __syncthreads();

    // P[r*129+c] = #points in row r with ix0 < c
    if (tid < 128) {
        uint_t acc = 0;
        P[tid * 129 + 0] = 0;
        for (int c = 0; c < 128; ++c) {
            acc += SH[(tid << 7) + c];
            P[tid * 129 + c + 1] = (ushort_t)acc;
        }
    }
    __syncthreads();

    // deterministic rank among same-(iy0,ix0) points, by pid
    int rank = 0;
    for (int p = 0; p < N_PTS; ++p)
        rank += (p < tid && cell0tab[p] == (ushort_t)cell0) ? 1 : 0;

    // per-cell list length (overwrites SH; H is dead) + length histogram
    for (int i = tid; i < N_CELLS; i += 1024) {
        int iy = i >> 7, ix = i & 127;
        int rlo = max(iy - 10, 0), rhi = min(iy, OUT_D - WIN);
        int clo = max(ix - 10, 0), chi = min(ix, OUT_D - WIN);
        uint_t len = 0;
        for (int r = rlo; r <= rhi; ++r)
            len += (uint_t)P[r * 129 + chi + 1] - (uint_t)P[r * 129 + clo];
        SH[i] = len;
        atomicAdd(&bins[len], 1u);
    }
    __syncthreads();
    if (tid == 0) {                         // descending-length start offsets
        uint_t acc = 0;
        for (int L = 1024; L >= 0; --L) { uint_t t = bins[L]; bins[L] = acc; acc += t; }
    }
    __syncthreads();
    for (int i = tid; i < N_CELLS; i += 1024) {   // assign sorted slots
        uint_t len = SH[i];
        uint_t slot = atomicAdd(&bins[len], 1u);
        SH[i] = len | (slot << 16);
        cellof_l[slot] = (ushort_t)i;
    }
    __syncthreads();
    if (tid < 256) cbase_l[tid] = SH[cellof_l[tid * 64]] & 0xFFFFu; // stash chunk maxlen
    __syncthreads();
    if (tid == 0) {
        uint_t acc = 0;
        for (int c = 0; c < 256; ++c) { uint_t l = cbase_l[c]; cbase_l[c] = acc; acc += l * 64u; }
        cbase_l[256] = acc;
    }
    __syncthreads();
    // export tables
    for (int i = tid; i < N_CELLS; i += 1024) cellofg[img * N_CELLS + i] = cellof_l[i];
    if (tid < 256) {
        cbaseg[img * 257 + tid] = cbase_l[tid];
        cleng[img * 256 + tid]  = SH[cellof_l[tid * 64]] & 0xFFFFu;
    }
    if (tid == 0) cbaseg[img * 257 + 256] = cbase_l[256];

    // fill stream (scattered global writes, once)
    uint_t* simg = stream + (size_t)img * STREAM_CAP;
    for (int j = 0; j < WIN; ++j) {
        int iyc = iy0 + j;
        for (int k = 0; k < WIN; ++k) {
            int ixc = ix0 + k;
            int cell = (iyc << 7) | ixc;
            int clo = max(ixc - 10, 0), chi = min(ixc, OUT_D - WIN);
            int rlo = max(iyc - 10, 0);
            uint_t idx = (uint_t)rank;
            for (int r = rlo; r < iy0; ++r)
                idx += (uint_t)P[r * 129 + chi + 1] - (uint_t)P[r * 129 + clo];
            idx += (uint_t)P[iy0 * 129 + ix0] - (uint_t)P[iy0 * 129 + clo];
            uint_t slot = SH[cell] >> 16;
            uint_t wofs = cbase_l[slot >> 6] + idx * 64u + (slot & 63u);
            simg[wofs] = ((uint_t)f2bf(ky[j] * kx[k]) << 16) | (uint_t)tid;
        }
    }
}

// ------------------------------------------------------------ main kernel --
__device__ __forceinline__ float blk_sum(float v, volatile float* red)
{
#pragma unroll
    for (int o = 32; o; o >>= 1) v += __shfl_xor(v, o, 64);
    int wave = threadIdx.x >> 6, lane = threadIdx.x & 63;
    if (lane == 0) red[wave] = v;
    __syncthreads();
    if (threadIdx.x < 64) {
        float t = (lane < 16) ? red[lane] : 0.0f;
#pragma unroll
        for (int o = 8; o; o >>= 1) t += __shfl_xor(t, o, 64);
        if (lane == 0) red[0] = t;
    }
    __syncthreads();
    float r = red[0];
    __syncthreads();
    return r;
}

__global__ __launch_bounds__(1024, 4) void ot_fused(
    const float* __restrict__ nd, const float* __restrict__ und,
    const float* __restrict__ pts, const uint_t* __restrict__ stream,
    const uint_t* __restrict__ cellofg, const uint_t* __restrict__ cbaseg,
    const uint_t* __restrict__ cleng, float* __restrict__ parts)
{
    __shared__ float  Vf[N_CELLS];      // 64KB  v (f32)
    __shared__ float  su[N_PTS];        // 4KB   published u
    __shared__ uint_t cbase_l[257];
    __shared__ uint_t clen_l[256];
    __shared__ float  red[64];

    const int img = blockIdx.x, tid = threadIdx.x, w = tid >> 6;
    const float* ndi = nd + img * N_CELLS;
    if (tid < 257) cbase_l[tid] = cbaseg[img * 257 + tid];
    if (tid < 256) clen_l[tid]  = cleng[img * 256 + tid];
    su[tid] = INV_N;

    // per-slot static data (thread owns 16 sorted slots)
    int   cellid[16];
    float b_r[16];
#pragma unroll
    for (int r = 0; r < 16; ++r) {
        int slot = r * 1024 + tid;
        cellid[r] = (int)cellofg[img * N_CELLS + slot];
        b_r[r]    = ndi[cellid[r]];
    }

    // per-point static data (thread owns point tid)
    const float x = pts[(img * N_PTS + tid) * 2 + 0];
    const float y = pts[(img * N_PTS + tid) * 2 + 1];
    const int nx = (int)floorf((x - 2.f) * 0.25f + 0.5f);
    const int ny = (int)floorf((y - 2.f) * 0.25f + 0.5f);
    const int ix0 = min(max(nx - RT, 0), OUT_D - WIN);
    const int iy0 = min(max(ny - RT, 0), OUT_D - WIN);
    const float xx = x * x, yy = y * y;
    float kxr[WIN], kyr[WIN];
#pragma unroll
    for (int k = 0; k < WIN; ++k) {
        float cx = (float)(4 * (ix0 + k) + 2);
        kxr[k] = __expf(-((xx - 2.f * x * cx) + cx * cx) * 0.1f);
        float cy = (float)(4 * (iy0 + k) + 2);
        kyr[k] = __expf(-((yy - 2.f * y * cy) + cy * cy) * 0.1f);
    }
    float u = INV_N;
    const float* vb = &Vf[iy0 * OUT_D + ix0];
    const uint_t* simg = stream + (size_t)img * STREAM_CAP;
    __syncthreads();

    // ---- Sinkhorn main loop ----------------------------------------------
    for (int it = 0; it < N_ITERS; ++it) {
        // phase A: per-cell gather. 1 stream load + 1 su read + fma per pair.
        float acc[16];
#pragma unroll
        for (int r = 0; r < 16; ++r) {
            int chunk = (r << 4) | w;                 // wave-uniform
            const uint_t* sp = simg + cbase_l[chunk] + (tid & 63);
            int len = (int)clen_l[chunk];
            float a = 0.f;
            for (int t = 0; t < len; ++t) {
                uint_t e = sp[t * 64];
                a = fmaf(su[e & 1023u], __uint_as_float(e & 0xFFFF0000u), a);
            }
            acc[r] = a;
        }
#pragma unroll
        for (int r = 0; r < 16; ++r)
            Vf[cellid[r]] = b_r[r] / (acc[r] + EPS);
        __syncthreads();

        // phase B: per-point 121-tap gather (single vaddr + imm offsets)
        float t_ = 0.f;
#pragma unroll
        for (int j = 0; j < WIN; ++j) {
            float rs = 0.f;
#pragma unroll
            for (int k = 0; k < WIN; ++k) rs = fmaf(kxr[k], vb[j * OUT_D + k], rs);
            t_ = fmaf(kyr[j], rs, t_);
        }
        u = INV_N / (t_ + EPS);
        su[tid] = u;
        __syncthreads();
    }

    // ---- epilogue ----------------------------------------------------------
    const float* sdi = und + img * N_CELLS;
    float sc = 0.f, T = 0.f, ot = 0.f;
#pragma unroll
    for (int r = 0; r < 16; ++r) {
        int c = r * 1024 + tid;
        float beta = 10.0f * logf(Vf[c] + EPS);
        float s = sdi[c];
        sc += s;
        T  = fmaf(s, beta, T);
        ot = fmaf(ndi[c], beta, ot);
    }
    sc = blk_sum(sc, red);
    T  = blk_sum(T,  red);
    ot = blk_sum(ot, red);
    float denom = sc * sc + 1e-8f;
    float c1 = sc / denom, c2 = T / denom;

    float loss = 0.f;
#pragma unroll
    for (int r = 0; r < 16; ++r) {
        int c = r * 1024 + tid;
        float beta = 10.0f * logf(Vf[c] + EPS);
        loss = fmaf(sdi[c], fmaf(c1, beta, -c2), loss);
    }
    loss = blk_sum(loss, red);

    // wd = u_n * sum_window (dy+dx)*Ky*Kx*v (exact f32 taps)
    float wd = 0.f;
#pragma unroll
    for (int j = 0; j < WIN; ++j) {
        float cy = (float)(4 * (iy0 + j) + 2);
        float dy = (yy - 2.f * y * cy) + cy * cy;
        float skv = 0.f, sdkv = 0.f;
#pragma unroll
        for (int k = 0; k < WIN; ++k) {
            float cx = (float)(4 * (ix0 + k) + 2);
            float dx = (xx - 2.f * x * cx) + cx * cx;
            float kv = kxr[k] * vb[j * OUT_D + k];
            skv += kv;
            sdkv = fmaf(dx, kv, sdkv);
        }
        wd = fmaf(kyr[j], fmaf(dy, skv, sdkv), wd);
    }
    wd *= u;
    wd = blk_sum(wd, red);

    if (tid == 0) {
        parts[img * 3 + 0] = loss;
        parts[img * 3 + 1] = wd;
        parts[img * 3 + 2] = ot;
    }
}

__global__ void ot_sum(const float* __restrict__ parts, float* __restrict__ out)
{
    int t = threadIdx.x;
    if (t < 3) {
        float s = 0.f;
        for (int i = 0; i < N_IMG; ++i) s += parts[i * 3 + t];
        out[t] = s;
    }
}

// ---------------------------------------------------------------- launch ---
extern "C" void kernel_launch(void* const* d_in, const int* in_sizes, int n_in,
                              void* d_out, int out_size, void* d_ws, size_t ws_size,
                              hipStream_t stream_)
{
    const float* nd  = (const float*)d_in[0];   // normed_density  [8][16384]
    const float* und = (const float*)d_in[1];   // unnormed_density[8][16384]
    const float* pts = (const float*)d_in[2];   // points          [8][1024][2]

    uint_t* stream  = (uint_t*)d_ws;                        // 16MB
    uint_t* cellofg = stream  + (size_t)N_IMG * STREAM_CAP; // 512KB
    uint_t* cbaseg  = cellofg + N_IMG * N_CELLS;
    uint_t* cleng   = cbaseg  + N_IMG * 257;
    float*  parts   = (float*)(cleng + N_IMG * 256);
    // total ~16.6MB of workspace

    hipMemsetAsync(stream, 0, (size_t)N_IMG * STREAM_CAP * 4, stream_); // zero pads
    ot_build<<<N_IMG, 1024, 0, stream_>>>(pts, stream, cellofg, cbaseg, cleng);
    ot_fused<<<N_IMG, 1024, 0, stream_>>>(nd, und, pts, stream, cellofg, cbaseg,
                                          cleng, parts);
    ot_sum<<<1, 64, 0, stream_>>>(parts, (float*)d_out);
}

// Round 5
// 1536.658 us; speedup vs baseline: 10.6747x; 1.4062x over previous
//
#include <hip/hip_runtime.h>

// Fused OT Sinkhorn, MI355X — round 5: quad-cell CSR + bank-scheduled su reads
// + wide bf16 phase-B reads.
// Round-4 counters: 1.46e7 LDS bank-conflict cycles + 124K ds_read_b32/iter
// were ~12us of the 20us iter. Fixes:
//  (1) QUAD lists: entry covers 4 adjacent cells (coeff4 = 2 u32 of bf16);
//      one su[pid] read feeds 4 FMAs -> 3.2x fewer LDS wave-ops.
//  (2) builder sorts each quad list by ((pid&31)-(lane&31))&31 so column t
//      across 64 lanes hits distinct banks (rotation schedule).
//  (3) v as bf16 in LDS; phase B reads 18-wide 8-aligned x-window as
//      2x ds_read_b128 + b32 per row (3 ops vs 11), bank-balanced by width.

#define N_IMG   8
#define N_PTS   1024
#define OUT_D   128
#define N_CELLS (OUT_D * OUT_D)
#define WIN     11
#define RT      5
#define WINX    18
#define NQUAD   4096
#define NCHUNK  64
#define CAPE    131072          // stream entries per image
#define EPS     1e-16f
#define INV_N   (1.0f / 1024.0f)
#define N_ITERS 100

typedef unsigned int   uint_t;
typedef unsigned short u16;

__device__ __forceinline__ u16 f2bf(float f) {      // RNE f32->bf16
    uint_t b = __float_as_uint(f);
    b += 0x7FFFu + ((b >> 16) & 1u);
    return (u16)(b >> 16);
}
__device__ __forceinline__ float bf2f(u16 h)   { return __uint_as_float(((uint_t)h) << 16); }
__device__ __forceinline__ float bflo(uint_t w){ return __uint_as_float(w << 16); }
__device__ __forceinline__ float bfhi(uint_t w){ return __uint_as_float(w & 0xFFFF0000u); }

// ---------------------------------------------------------------- builder --
__global__ __launch_bounds__(1024) void ot_build(
    const float* __restrict__ pts, uint2* __restrict__ cstream,
    u16* __restrict__ pstream, u16* __restrict__ qofslotg,
    uint_t* __restrict__ cbaseg, uint_t* __restrict__ cleng)
{
    __shared__ uint_t chist[N_CELLS];      // 64KB
    __shared__ u16    P[128 * 129];        // 33KB: P[r][c] = #pts row r, ix0 < c
    __shared__ u16    c0tab[N_PTS];
    __shared__ u16    qslot[NQUAD];
    __shared__ u16    qlen[NQUAD];
    __shared__ u16    qofslot[NQUAD];
    __shared__ uint_t bins[1025];
    __shared__ uint_t cbase_l[NCHUNK + 1];

    const int img = blockIdx.x, tid = threadIdx.x;
    for (int i = tid; i < N_CELLS; i += 1024) chist[i] = 0;
    for (int i = tid; i < 1025;    i += 1024) bins[i] = 0;
    __syncthreads();

    const float x = pts[(img * N_PTS + tid) * 2 + 0];
    const float y = pts[(img * N_PTS + tid) * 2 + 1];
    const int nx = (int)floorf((x - 2.f) * 0.25f + 0.5f);
    const int ny = (int)floorf((y - 2.f) * 0.25f + 0.5f);
    const int ix0 = min(max(nx - RT, 0), OUT_D - WIN);
    const int iy0 = min(max(ny - RT, 0), OUT_D - WIN);
    const float xx = x * x, yy = y * y;
    float kx[WIN], ky[WIN];
#pragma unroll
    for (int k = 0; k < WIN; ++k) {        // mimic reference's x^2-2xc+c^2
        float cx = (float)(4 * (ix0 + k) + 2);
        kx[k] = __expf(-((xx - 2.f * x * cx) + cx * cx) * 0.1f);
        float cy = (float)(4 * (iy0 + k) + 2);
        ky[k] = __expf(-((yy - 2.f * y * cy) + cy * cy) * 0.1f);
    }
    const int cell0 = (iy0 << 7) | ix0;
    c0tab[tid] = (u16)cell0;
    atomicAdd(&chist[cell0], 1u);
    __syncthreads();

    if (tid < 128) {
        uint_t acc = 0;
        P[tid * 129 + 0] = 0;
        for (int c = 0; c < 128; ++c) { acc += chist[(tid << 7) + c]; P[tid * 129 + c + 1] = (u16)acc; }
    }
    __syncthreads();

    int rank = 0;                          // rank among same-(iy0,ix0) pts by pid
    for (int p = 0; p < N_PTS; ++p) rank += (p < tid && c0tab[p] == (u16)cell0) ? 1 : 0;

    // quad list lengths + length histogram
    for (int i = tid; i < NQUAD; i += 1024) {
        int iy = i >> 5, qx = i & 31;
        int clo = max(4 * qx - 10, 0), chi = min(4 * qx + 3, OUT_D - WIN);
        int rlo = max(iy - 10, 0), rhi = min(iy, OUT_D - WIN);
        uint_t len = 0;
        for (int r = rlo; r <= rhi; ++r)
            len += (uint_t)P[r * 129 + chi + 1] - (uint_t)P[r * 129 + clo];
        qlen[i] = (u16)len;
        atomicAdd(&bins[len], 1u);
    }
    __syncthreads();
    if (tid == 0) {                        // desc-length exclusive offsets
        uint_t acc = 0;
        for (int L = 1024; L >= 0; --L) { uint_t t = bins[L]; bins[L] = acc; acc += t; }
    }
    __syncthreads();
    for (int i = tid; i < NQUAD; i += 1024) {
        uint_t slot = atomicAdd(&bins[qlen[i]], 1u);
        qslot[i] = (u16)slot;
        qofslot[slot] = (u16)i;
    }
    __syncthreads();
    if (tid < NCHUNK) cbase_l[tid] = qlen[qofslot[tid * 64]];   // chunk maxlen
    __syncthreads();
    if (tid == 0) {
        uint_t acc = 0;
        for (int c = 0; c < NCHUNK; ++c) { uint_t l = cbase_l[c]; cbase_l[c] = acc; acc += l * 64u; }
        cbase_l[NCHUNK] = acc;
    }
    __syncthreads();
    for (int i = tid; i < NQUAD; i += 1024) qofslotg[img * NQUAD + i] = qofslot[i];
    if (tid < NCHUNK) {
        cbaseg[img * NCHUNK + tid] = cbase_l[tid];
        cleng[img * NCHUNK + tid]  = qlen[qofslot[tid * 64]];
    }

    // fill streams (deterministic positions via P + rank)
    uint2* cs = cstream + (size_t)img * CAPE;
    u16*   ps = pstream + (size_t)img * CAPE;
    const int qxa = ix0 >> 2, qxb = min((ix0 + 10) >> 2, 31);
    for (int j = 0; j < WIN; ++j) {
        int iy = iy0 + j;
        for (int qx = qxa; qx <= qxb; ++qx) {
            int quad = (iy << 5) | qx;
            int slot = qslot[quad];
            int clo = max(4 * qx - 10, 0), chi = min(4 * qx + 3, OUT_D - WIN);
            int rlo = max(iy - 10, 0);
            uint_t idx = (uint_t)rank + (uint_t)P[iy0 * 129 + ix0] - (uint_t)P[iy0 * 129 + clo];
            for (int r = rlo; r < iy0; ++r)
                idx += (uint_t)P[r * 129 + chi + 1] - (uint_t)P[r * 129 + clo];
            uint_t eofs = cbase_l[slot >> 6] + idx * 64u + (uint_t)(slot & 63);
            if (eofs < CAPE - 64) {
                int d0 = 4 * qx - ix0;     // tap of quad col 0, in [-3,10]
                float c0 = ((unsigned)(d0 + 0) < 11u) ? ky[j] * kx[d0 + 0] : 0.f;
                float c1 = ((unsigned)(d0 + 1) < 11u) ? ky[j] * kx[d0 + 1] : 0.f;
                float c2 = ((unsigned)(d0 + 2) < 11u) ? ky[j] * kx[d0 + 2] : 0.f;
                float c3 = ((unsigned)(d0 + 3) < 11u) ? ky[j] * kx[d0 + 3] : 0.f;
                cs[eofs] = make_uint2((uint_t)f2bf(c0) | ((uint_t)f2bf(c1) << 16),
                                      (uint_t)f2bf(c2) | ((uint_t)f2bf(c3) << 16));
                ps[eofs] = (u16)tid;
            }
        }
    }
    __syncthreads();                       // barrier drains vmem (same-CU L1)

    // bank-rotation sort: column t across 64 lanes -> distinct su banks
    for (int r = 0; r < 4; ++r) {
        int s = r * 1024 + tid;            // lane = s&63 = tid&63
        int quad = qofslot[s];
        int len = qlen[quad];
        if (len < 2 || len > 48) continue;
        uint2* csb = cs + cbase_l[s >> 6] + (s & 63);
        u16*   psb = ps + cbase_l[s >> 6] + (s & 63);
        uint2 ce[48]; u16 pe[48]; int ke[48];
        for (int t = 0; t < len; ++t) {
            ce[t] = csb[(size_t)t * 64];
            pe[t] = psb[(size_t)t * 64];
            ke[t] = (int)((((uint_t)pe[t] & 31u) - ((uint_t)tid & 31u)) & 31u);
        }
        for (int i = 1; i < len; ++i) {    // insertion sort (one-time, scratch ok)
            uint2 cv = ce[i]; u16 pv = pe[i]; int kv = ke[i]; int j2 = i - 1;
            while (j2 >= 0 && ke[j2] > kv) {
                ce[j2 + 1] = ce[j2]; pe[j2 + 1] = pe[j2]; ke[j2 + 1] = ke[j2]; --j2;
            }
            ce[j2 + 1] = cv; pe[j2 + 1] = pv; ke[j2 + 1] = kv;
        }
        for (int t = 0; t < len; ++t) {
            csb[(size_t)t * 64] = ce[t];
            psb[(size_t)t * 64] = pe[t];
        }
    }
}

// ------------------------------------------------------------ main kernel --
__device__ __forceinline__ float blk_sum(float v, volatile float* red)
{
#pragma unroll
    for (int o = 32; o; o >>= 1) v += __shfl_xor(v, o, 64);
    int wave = threadIdx.x >> 6, lane = threadIdx.x & 63;
    if (lane == 0) red[wave] = v;
    __syncthreads();
    if (threadIdx.x < 64) {
        float t = (lane < 16) ? red[lane] : 0.0f;
#pragma unroll
        for (int o = 8; o; o >>= 1) t += __shfl_xor(t, o, 64);
        if (lane == 0) red[0] = t;
    }
    __syncthreads();
    float r = red[0];
    __syncthreads();
    return r;
}

__global__ __launch_bounds__(1024) void ot_fused(
    const float* __restrict__ nd, const float* __restrict__ und,
    const float* __restrict__ pts, const uint2* __restrict__ cstream,
    const u16* __restrict__ pstream, const u16* __restrict__ qofslotg,
    const uint_t* __restrict__ cbaseg, const uint_t* __restrict__ cleng,
    float* __restrict__ parts)
{
    __shared__ u16    Vh[N_CELLS + 32];    // 32KB bf16 v (+zero pad for edge b128)
    __shared__ float  su[N_PTS];           // 4KB
    __shared__ uint_t cbase_l[NCHUNK];
    __shared__ uint_t clen_l[NCHUNK];
    __shared__ float  red[64];

    const int img = blockIdx.x, tid = threadIdx.x;
    const int w = tid >> 6, lane = tid & 63;
    const float* ndi = nd + img * N_CELLS;

    if (tid < NCHUNK) { cbase_l[tid] = cbaseg[img * NCHUNK + tid]; clen_l[tid] = cleng[img * NCHUNK + tid]; }
    if (tid < 32) Vh[N_CELLS + tid] = 0;
    su[tid] = INV_N;
    __syncthreads();

    // phase-A ownership: thread owns 4 sorted quads
    int    qcell[4]; float4 b4[4];
    const uint2* csb[4]; const u16* psb[4]; int clen_r[4];
#pragma unroll
    for (int r = 0; r < 4; ++r) {
        int q = (int)qofslotg[img * NQUAD + r * 1024 + tid];
        qcell[r] = (q >> 5) * OUT_D + (q & 31) * 4;
        b4[r] = *(const float4*)(ndi + qcell[r]);
        int ch = r * 16 + w;
        csb[r] = cstream + (size_t)img * CAPE + cbase_l[ch] + lane;
        psb[r] = pstream + (size_t)img * CAPE + cbase_l[ch] + lane;
        clen_r[r] = (int)clen_l[ch];
    }

    // phase-B per-point data (thread = point tid)
    const float x = pts[(img * N_PTS + tid) * 2 + 0];
    const float y = pts[(img * N_PTS + tid) * 2 + 1];
    const int nx = (int)floorf((x - 2.f) * 0.25f + 0.5f);
    const int ny = (int)floorf((y - 2.f) * 0.25f + 0.5f);
    const int ix0 = min(max(nx - RT, 0), OUT_D - WIN);
    const int iy0 = min(max(ny - RT, 0), OUT_D - WIN);
    const int ixq = ix0 & ~7;              // 8-aligned -> 16B-aligned LDS rows
    const float xx = x * x, yy = y * y;
    float kxr[WINX], kyr[WIN];
#pragma unroll
    for (int d = 0; d < WINX; ++d) {
        int col = ixq + d;
        float cx = (float)(4 * col + 2);
        kxr[d] = (col < OUT_D) ? __expf(-((xx - 2.f * x * cx) + cx * cx) * 0.1f) : 0.f;
    }
#pragma unroll
    for (int j = 0; j < WIN; ++j) {
        float cy = (float)(4 * (iy0 + j) + 2);
        kyr[j] = __expf(-((yy - 2.f * y * cy) + cy * cy) * 0.1f);
    }
    float ureg = INV_N;
    const u16* vb = &Vh[iy0 * OUT_D + ixq];

    // ---- Sinkhorn main loop ----------------------------------------------
    for (int it = 0; it < N_ITERS; ++it) {
        // phase A: quad gather, prefetch-1 (pad entries are zeroed -> safe)
#pragma unroll
        for (int r = 0; r < 4; ++r) {
            const uint2* cs = csb[r]; const u16* ps = psb[r];
            int len = clen_r[r];
            float a0 = 0.f, a1 = 0.f, a2 = 0.f, a3 = 0.f;
            uint2 cw = make_uint2(0u, 0u); u16 pid = 0;
            if (len > 0) { cw = cs[0]; pid = ps[0]; }
            for (int t = 1; t <= len; ++t) {
                uint2 cwn = cs[(size_t)t * 64];
                u16  pn  = ps[(size_t)t * 64];
                float uv = su[pid];
                a0 = fmaf(uv, bflo(cw.x), a0);
                a1 = fmaf(uv, bfhi(cw.x), a1);
                a2 = fmaf(uv, bflo(cw.y), a2);
                a3 = fmaf(uv, bfhi(cw.y), a3);
                cw = cwn; pid = pn;
            }
            float4 b = b4[r];
            uint_t lo = (uint_t)f2bf(b.x / (a0 + EPS)) | ((uint_t)f2bf(b.y / (a1 + EPS)) << 16);
            uint_t hi = (uint_t)f2bf(b.z / (a2 + EPS)) | ((uint_t)f2bf(b.w / (a3 + EPS)) << 16);
            *(uint2*)&Vh[qcell[r]] = make_uint2(lo, hi);
        }
        __syncthreads();

        // phase B: 18-wide rows, 2x b128 + b32 per row
        float t_ = 0.f;
#pragma unroll
        for (int j = 0; j < WIN; ++j) {
            const u16* row = vb + j * OUT_D;
            uint4 w0 = *(const uint4*)(row);
            uint4 w1 = *(const uint4*)(row + 8);
            uint_t w2 = *(const uint_t*)(row + 16);
            float rs;
            rs = kxr[0] * bflo(w0.x);
            rs = fmaf(kxr[1],  bfhi(w0.x), rs);
            rs = fmaf(kxr[2],  bflo(w0.y), rs);
            rs = fmaf(kxr[3],  bfhi(w0.y), rs);
            rs = fmaf(kxr[4],  bflo(w0.z), rs);
            rs = fmaf(kxr[5],  bfhi(w0.z), rs);
            rs = fmaf(kxr[6],  bflo(w0.w), rs);
            rs = fmaf(kxr[7],  bfhi(w0.w), rs);
            rs = fmaf(kxr[8],  bflo(w1.x), rs);
            rs = fmaf(kxr[9],  bfhi(w1.x), rs);
            rs = fmaf(kxr[10], bflo(w1.y), rs);
            rs = fmaf(kxr[11], bfhi(w1.y), rs);
            rs = fmaf(kxr[12], bflo(w1.z), rs);
            rs = fmaf(kxr[13], bfhi(w1.z), rs);
            rs = fmaf(kxr[14], bflo(w1.w), rs);
            rs = fmaf(kxr[15], bfhi(w1.w), rs);
            rs = fmaf(kxr[16], bflo(w2),   rs);
            rs = fmaf(kxr[17], bfhi(w2),   rs);
            t_ = fmaf(kyr[j], rs, t_);
        }
        ureg = INV_N / (t_ + EPS);
        su[tid] = ureg;
        __syncthreads();
    }

    // ---- epilogue ---------------------------------------------------------
    const float* sdi = und + img * N_CELLS;
    float sc = 0.f, T = 0.f, ot = 0.f;
#pragma unroll
    for (int r = 0; r < 16; ++r) {
        int c = r * 1024 + tid;
        float beta = 10.0f * logf(bf2f(Vh[c]) + EPS);
        float s = sdi[c];
        sc += s;
        T  = fmaf(s, beta, T);
        ot = fmaf(ndi[c], beta, ot);
    }
    sc = blk_sum(sc, red);
    T  = blk_sum(T,  red);
    ot = blk_sum(ot, red);
    float denom = sc * sc + 1e-8f;
    float c1 = sc / denom, c2 = T / denom;

    float loss = 0.f;
#pragma unroll
    for (int r = 0; r < 16; ++r) {
        int c = r * 1024 + tid;
        float beta = 10.0f * logf(bf2f(Vh[c]) + EPS);
        loss = fmaf(sdi[c], fmaf(c1, beta, -c2), loss);
    }
    loss = blk_sum(loss, red);

    // wd = u_n * sum_window (dy+dx)*Ky*Kx*v  (18-tap x-window, kx=0 off-grid)
    float wd = 0.f;
#pragma unroll
    for (int j = 0; j < WIN; ++j) {
        float cy = (float)(4 * (iy0 + j) + 2);
        float dy = (yy - 2.f * y * cy) + cy * cy;
        const u16* row = vb + j * OUT_D;
        float skv = 0.f, sdkv = 0.f;
#pragma unroll
        for (int d = 0; d < WINX; ++d) {
            float cx = (float)(4 * (ixq + d) + 2);
            float dx = (xx - 2.f * x * cx) + cx * cx;
            float kv = kxr[d] * bf2f(row[d]);
            skv += kv;
            sdkv = fmaf(dx, kv, sdkv);
        }
        wd = fmaf(kyr[j], fmaf(dy, skv, sdkv), wd);
    }
    wd *= ureg;
    wd = blk_sum(wd, red);

    if (tid == 0) {
        parts[img * 3 + 0] = loss;
        parts[img * 3 + 1] = wd;
        parts[img * 3 + 2] = ot;
    }
}

__global__ void ot_sum(const float* __restrict__ parts, float* __restrict__ out)
{
    int t = threadIdx.x;
    if (t < 3) {
        float s = 0.f;
        for (int i = 0; i < N_IMG; ++i) s += parts[i * 3 + t];
        out[t] = s;
    }
}

// ---------------------------------------------------------------- launch ---
extern "C" void kernel_launch(void* const* d_in, const int* in_sizes, int n_in,
                              void* d_out, int out_size, void* d_ws, size_t ws_size,
                              hipStream_t stream_)
{
    const float* nd  = (const float*)d_in[0];   // normed_density  [8][16384]
    const float* und = (const float*)d_in[1];   // unnormed_density[8][16384]
    const float* pts = (const float*)d_in[2];   // points          [8][1024][2]

    char* ws = (char*)d_ws;
    uint2*  cstream  = (uint2*)ws;                          // 8*131072*8 = 8388608
    u16*    pstream  = (u16*)(ws + 8388608);                // 2097152
    u16*    qofslotg = (u16*)(ws + 10485760);               // 65536
    uint_t* cbaseg   = (uint_t*)(ws + 10551296);            // 2048
    uint_t* cleng    = (uint_t*)(ws + 10553344);            // 2048
    float*  parts    = (float*)(ws + 10555392);             // 96
    // total ~10.6MB

    hipMemsetAsync(cstream, 0, 10485760, stream_);          // zero both streams (pads)
    ot_build<<<N_IMG, 1024, 0, stream_>>>(pts, cstream, pstream, qofslotg, cbaseg, cleng);
    ot_fused<<<N_IMG, 1024, 0, stream_>>>(nd, und, pts, cstream, pstream, qofslotg,
                                          cbaseg, cleng, parts);
    ot_sum<<<1, 64, 0, stream_>>>(parts, (float*)d_out);
}

// Round 7
// 846.273 us; speedup vs baseline: 19.3831x; 1.8158x over previous
//
#include <hip/hip_runtime.h>

// Fused OT Sinkhorn, MI355X — round 7: round-6 design + builder init fix.
// (Round 6 crashed: bins[1024] left uninitialized by `if(tid<1025)` with
// 1024 threads -> garbage prefix -> out-of-bounds LDS writes -> abort.
// Fixed with strided zeroing. Design unchanged: 4x4-tile CSR, 16 MACs per
// entry; f32 V + 14-wide phase B (no bf16 unpack); packed float2 math.)

#define N_IMG   8
#define N_PTS   1024
#define OUT_D   128
#define N_CELLS (OUT_D * OUT_D)
#define WIN     11
#define RT      5
#define WINX    14
#define N_TILE  1024            // 32x32 tiles of 4x4 cells
#define N_CHUNK 16
#define CAPE    32768           // stream entries per image (slack; ~15K used)
#define EPS     1e-16f
#define INV_N   (1.0f / 1024.0f)
#define N_ITERS 100

typedef unsigned int   uint_t;
typedef unsigned short u16;
typedef float v2f __attribute__((ext_vector_type(2)));

__device__ __forceinline__ u16 f2bf(float f) {      // RNE f32->bf16
    uint_t b = __float_as_uint(f);
    b += 0x7FFFu + ((b >> 16) & 1u);
    return (u16)(b >> 16);
}
__device__ __forceinline__ float bflo(uint_t w){ return __uint_as_float(w << 16); }
__device__ __forceinline__ float bfhi(uint_t w){ return __uint_as_float(w & 0xFFFF0000u); }

// ---------------------------------------------------------------- builder --
// One WG per image. Deterministic entry positions (no heavy atomics):
// tile list order = (iy0 asc, ix0 asc, pid asc) via row-prefix table P.
__global__ __launch_bounds__(1024) void ot_build(
    const float* __restrict__ pts, uint4* __restrict__ cstream,
    u16* __restrict__ pstream, u16* __restrict__ tileofg,
    uint_t* __restrict__ cbaseg, uint_t* __restrict__ cleng)
{
    __shared__ uint_t chist[N_CELLS];      // 64KB
    __shared__ u16    P[128 * 129];        // 33KB  P[r][c] = #pts row r, ix0 < c
    __shared__ u16    c0tab[N_PTS];
    __shared__ u16    tslot[N_TILE];
    __shared__ u16    tlen[N_TILE];
    __shared__ u16    tof[N_TILE];
    __shared__ uint_t bins[1025];
    __shared__ uint_t cbase_l[N_CHUNK + 1];

    const int img = blockIdx.x, tid = threadIdx.x;
    for (int i = tid; i < N_CELLS; i += 1024) chist[i] = 0;
    for (int i = tid; i < 1025;    i += 1024) bins[i] = 0;   // FIX: covers bins[1024]
    __syncthreads();

    const float x = pts[(img * N_PTS + tid) * 2 + 0];
    const float y = pts[(img * N_PTS + tid) * 2 + 1];
    const int nx = (int)floorf((x - 2.f) * 0.25f + 0.5f);
    const int ny = (int)floorf((y - 2.f) * 0.25f + 0.5f);
    const int ix0 = min(max(nx - RT, 0), OUT_D - WIN);
    const int iy0 = min(max(ny - RT, 0), OUT_D - WIN);
    const float xx = x * x, yy = y * y;
    float kx[WIN], ky[WIN];
#pragma unroll
    for (int k = 0; k < WIN; ++k) {        // mimic reference's x^2-2xc+c^2
        float cx = (float)(4 * (ix0 + k) + 2);
        kx[k] = __expf(-((xx - 2.f * x * cx) + cx * cx) * 0.1f);
        float cy = (float)(4 * (iy0 + k) + 2);
        ky[k] = __expf(-((yy - 2.f * y * cy) + cy * cy) * 0.1f);
    }
    const int cell0 = (iy0 << 7) | ix0;
    c0tab[tid] = (u16)cell0;
    atomicAdd(&chist[cell0], 1u);
    __syncthreads();

    if (tid < 128) {
        uint_t acc = 0;
        P[tid * 129 + 0] = 0;
        for (int c = 0; c < 128; ++c) { acc += chist[(tid << 7) + c]; P[tid * 129 + c + 1] = (u16)acc; }
    }
    __syncthreads();

    int rank = 0;                          // among same-(iy0,ix0), by pid
    for (int p = 0; p < N_PTS; ++p) rank += (p < tid && c0tab[p] == (u16)cell0) ? 1 : 0;

    // tile lengths (thread = tile) + length histogram
    {
        int ty = tid >> 5, tx = tid & 31;
        int rlo = max(4 * ty - 10, 0), rhi = min(4 * ty + 3, OUT_D - WIN);
        int xlo = max(4 * tx - 10, 0), xhi = min(4 * tx + 3, OUT_D - WIN);
        uint_t len = 0;
        for (int r = rlo; r <= rhi; ++r)
            len += (uint_t)P[r * 129 + xhi + 1] - (uint_t)P[r * 129 + xlo];
        tlen[tid] = (u16)len;
        atomicAdd(&bins[len], 1u);
    }
    __syncthreads();
    if (tid == 0) {                        // descending-length start offsets
        uint_t acc = 0;
        for (int L = 1024; L >= 0; --L) { uint_t t = bins[L]; bins[L] = acc; acc += t; }
    }
    __syncthreads();
    {
        uint_t slot = atomicAdd(&bins[tlen[tid]], 1u);
        tslot[tid] = (u16)slot;
        tof[slot] = (u16)tid;
    }
    __syncthreads();
    if (tid < N_CHUNK) cbase_l[tid] = tlen[tof[tid * 64]];   // chunk maxlen
    __syncthreads();
    if (tid == 0) {
        uint_t acc = 0;
        for (int c = 0; c < N_CHUNK; ++c) { uint_t l = cbase_l[c]; cbase_l[c] = acc; acc += l * 64u; }
        cbase_l[N_CHUNK] = acc;
    }
    __syncthreads();
    tileofg[img * N_TILE + tid] = tof[tid];
    if (tid < N_CHUNK) {
        cbaseg[img * N_CHUNK + tid] = cbase_l[tid];
        cleng[img * N_CHUNK + tid]  = tlen[tof[tid * 64]];
    }

    // fill streams
    uint4* cs = cstream + (size_t)img * CAPE;
    u16*   ps = pstream + (size_t)img * CAPE;
    const int tya = iy0 >> 2, tyb = (iy0 + 10) >> 2;
    const int txa = ix0 >> 2, txb = (ix0 + 10) >> 2;
    for (int ty = tya; ty <= tyb; ++ty) {
        for (int tx = txa; tx <= txb; ++tx) {
            int ti = (ty << 5) | tx;
            int slot = tslot[ti];
            int xlo = max(4 * tx - 10, 0), xhi = min(4 * tx + 3, OUT_D - WIN);
            int rlo = max(4 * ty - 10, 0);
            uint_t idx = (uint_t)rank + (uint_t)P[iy0 * 129 + ix0] - (uint_t)P[iy0 * 129 + xlo];
            for (int r = rlo; r < iy0; ++r)
                idx += (uint_t)P[r * 129 + xhi + 1] - (uint_t)P[r * 129 + xlo];
            uint_t eofs = cbase_l[slot >> 6] + idx * 64u + (uint_t)(slot & 63);
            if (eofs < CAPE) {
                u16 kxp[4], kyp[4];
#pragma unroll
                for (int c = 0; c < 4; ++c) {
                    int dk = 4 * tx + c - ix0;
                    kxp[c] = ((unsigned)dk < 11u) ? f2bf(kx[dk]) : (u16)0;
                    int dj = 4 * ty + c - iy0;
                    kyp[c] = ((unsigned)dj < 11u) ? f2bf(ky[dj]) : (u16)0;
                }
                cs[eofs] = make_uint4((uint_t)kxp[0] | ((uint_t)kxp[1] << 16),
                                      (uint_t)kxp[2] | ((uint_t)kxp[3] << 16),
                                      (uint_t)kyp[0] | ((uint_t)kyp[1] << 16),
                                      (uint_t)kyp[2] | ((uint_t)kyp[3] << 16));
                ps[eofs] = (u16)tid;
            }
        }
    }
}

// ------------------------------------------------------------ main kernel --
__device__ __forceinline__ float blk_sum(float v, volatile float* red)
{
#pragma unroll
    for (int o = 32; o; o >>= 1) v += __shfl_xor(v, o, 64);
    int wave = threadIdx.x >> 6, lane = threadIdx.x & 63;
    if (lane == 0) red[wave] = v;
    __syncthreads();
    if (threadIdx.x < 64) {
        float t = (lane < 16) ? red[lane] : 0.0f;
#pragma unroll
        for (int o = 8; o; o >>= 1) t += __shfl_xor(t, o, 64);
        if (lane == 0) red[0] = t;
    }
    __syncthreads();
    float r = red[0];
    __syncthreads();
    return r;
}

__global__ __launch_bounds__(1024) void ot_fused(
    const float* __restrict__ nd, const float* __restrict__ und,
    const float* __restrict__ pts, const uint4* __restrict__ cstream,
    const u16* __restrict__ pstream, const u16* __restrict__ tileofg,
    const uint_t* __restrict__ cbaseg, const uint_t* __restrict__ cleng,
    float* __restrict__ parts)
{
    __shared__ __align__(16) float V[N_CELLS + 16];   // 64KB f32 v + zero pad
    __shared__ float  su[N_PTS];                      // 4KB
    __shared__ uint_t cbase_l[N_CHUNK];
    __shared__ uint_t clen_l[N_CHUNK];
    __shared__ float  red[64];

    const int img = blockIdx.x, tid = threadIdx.x;
    const int w = tid >> 6, lane = tid & 63;
    const float* ndi = nd + img * N_CELLS;

    if (tid < N_CHUNK) { cbase_l[tid] = cbaseg[img * N_CHUNK + tid]; clen_l[tid] = cleng[img * N_CHUNK + tid]; }
    if (tid < 16) V[N_CELLS + tid] = 0.0f;
    su[tid] = INV_N;
    __syncthreads();

    // phase-A ownership: thread owns one 4x4 tile (sorted slot = w*64+lane)
    const int tile = (int)tileofg[img * N_TILE + w * 64 + lane];
    const int ty4 = (tile >> 5) * 4, tx4 = (tile & 31) * 4;
    float4 b4[4];
#pragma unroll
    for (int r = 0; r < 4; ++r) b4[r] = *(const float4*)(ndi + (ty4 + r) * OUT_D + tx4);
    const uint4* csb = cstream + (size_t)img * CAPE + cbase_l[w] + lane;
    const u16*   psb = pstream + (size_t)img * CAPE + cbase_l[w] + lane;
    const int    alen = (int)clen_l[w];               // wave-uniform

    // phase-B per-point data (thread = point tid)
    const float x = pts[(img * N_PTS + tid) * 2 + 0];
    const float y = pts[(img * N_PTS + tid) * 2 + 1];
    const int nx = (int)floorf((x - 2.f) * 0.25f + 0.5f);
    const int ny = (int)floorf((y - 2.f) * 0.25f + 0.5f);
    const int ix0 = min(max(nx - RT, 0), OUT_D - WIN);
    const int iy0 = min(max(ny - RT, 0), OUT_D - WIN);
    const int ixq = ix0 & ~3;                          // 16B-aligned window
    const float xx = x * x, yy = y * y;
    v2f kx2[WINX / 2], ky2[WIN];
#pragma unroll
    for (int d = 0; d < WINX; ++d) {
        int col = ixq + d, dk = col - ix0;
        float cx = (float)(4 * col + 2);
        float kv = ((unsigned)dk < 11u) ? __expf(-((xx - 2.f * x * cx) + cx * cx) * 0.1f) : 0.f;
        kx2[d >> 1][d & 1] = kv;
    }
#pragma unroll
    for (int j = 0; j < WIN; ++j) {
        float cy = (float)(4 * (iy0 + j) + 2);
        float kv = __expf(-((yy - 2.f * y * cy) + cy * cy) * 0.1f);
        ky2[j] = (v2f){kv, kv};
    }
    float ureg = INV_N;
    const float* vbp = &V[iy0 * OUT_D + ixq];

    // ---- Sinkhorn main loop ----------------------------------------------
    for (int it = 0; it < N_ITERS; ++it) {
        // phase A: 4x4-tile gather; entry = pid + ky4(x)kx4, 16 MACs
        v2f acc2[8] = {};
        uint4 cw = make_uint4(0u, 0u, 0u, 0u); u16 pid = 0;
        if (alen > 0) { cw = csb[0]; pid = psb[0]; }
        for (int t = 1; t <= alen; ++t) {
            uint4 cwn = csb[(size_t)t * 64];          // prefetch (pads zeroed,
            u16   pn  = psb[(size_t)t * 64];          //  CAPE has slack)
            float uv = su[pid & 1023u];
            v2f kxa = {bflo(cw.x), bfhi(cw.x)};
            v2f kxb = {bflo(cw.y), bfhi(cw.y)};
            float u0 = uv * bflo(cw.z), u1 = uv * bfhi(cw.z);
            float u2 = uv * bflo(cw.w), u3 = uv * bfhi(cw.w);
            v2f s0 = {u0, u0}, s1 = {u1, u1}, s2 = {u2, u2}, s3 = {u3, u3};
            acc2[0] += s0 * kxa;  acc2[1] += s0 * kxb;
            acc2[2] += s1 * kxa;  acc2[3] += s1 * kxb;
            acc2[4] += s2 * kxa;  acc2[5] += s2 * kxb;
            acc2[6] += s3 * kxa;  acc2[7] += s3 * kxb;
            cw = cwn; pid = pn;
        }
#pragma unroll
        for (int r = 0; r < 4; ++r) {                 // v = b * rcp(S+eps)
            float4 o;
            o.x = b4[r].x * __builtin_amdgcn_rcpf(acc2[2 * r][0] + EPS);
            o.y = b4[r].y * __builtin_amdgcn_rcpf(acc2[2 * r][1] + EPS);
            o.z = b4[r].z * __builtin_amdgcn_rcpf(acc2[2 * r + 1][0] + EPS);
            o.w = b4[r].w * __builtin_amdgcn_rcpf(acc2[2 * r + 1][1] + EPS);
            *(float4*)&V[(ty4 + r) * OUT_D + tx4] = o;
        }
        __syncthreads();

        // phase B: 14-wide f32 rows, 3x b128 + 1x b64, packed fma
        v2f t2 = {0.f, 0.f};
#pragma unroll
        for (int j = 0; j < WIN; ++j) {
            const float* row = vbp + j * OUT_D;
            float4 va = *(const float4*)(row);
            float4 vb = *(const float4*)(row + 4);
            float4 vc = *(const float4*)(row + 8);
            v2f    vd = *(const v2f*)(row + 12);
            v2f rs;
            rs  = kx2[0] * (v2f){va.x, va.y};
            rs += kx2[1] * (v2f){va.z, va.w};
            rs += kx2[2] * (v2f){vb.x, vb.y};
            rs += kx2[3] * (v2f){vb.z, vb.w};
            rs += kx2[4] * (v2f){vc.x, vc.y};
            rs += kx2[5] * (v2f){vc.z, vc.w};
            rs += kx2[6] * vd;
            t2 += ky2[j] * rs;
        }
        float tt = t2.x + t2.y;
        ureg = INV_N / (tt + EPS);
        su[tid] = ureg;
        __syncthreads();
    }

    // ---- epilogue ---------------------------------------------------------
    const float* sdi = und + img * N_CELLS;
    float sc = 0.f, T = 0.f, ot = 0.f;
#pragma unroll
    for (int r = 0; r < 16; ++r) {
        int c = r * 1024 + tid;
        float beta = 10.0f * logf(V[c] + EPS);
        float s = sdi[c];
        sc += s;
        T  = fmaf(s, beta, T);
        ot = fmaf(ndi[c], beta, ot);
    }
    sc = blk_sum(sc, red);
    T  = blk_sum(T,  red);
    ot = blk_sum(ot, red);
    float denom = sc * sc + 1e-8f;
    float c1 = sc / denom, c2 = T / denom;

    float loss = 0.f;
#pragma unroll
    for (int r = 0; r < 16; ++r) {
        int c = r * 1024 + tid;
        float beta = 10.0f * logf(V[c] + EPS);
        loss = fmaf(sdi[c], fmaf(c1, beta, -c2), loss);
    }
    loss = blk_sum(loss, red);

    // wd = u_n * sum_window (dy+dx)*Ky*Kx*v (14-tap x-window, kx=0 off-window)
    float wd = 0.f;
#pragma unroll
    for (int j = 0; j < WIN; ++j) {
        float cy = (float)(4 * (iy0 + j) + 2);
        float dy = (yy - 2.f * y * cy) + cy * cy;
        const float* row = vbp + j * OUT_D;
        float skv = 0.f, sdkv = 0.f;
#pragma unroll
        for (int d = 0; d < WINX; ++d) {
            float cx = (float)(4 * (ixq + d) + 2);
            float dx = (xx - 2.f * x * cx) + cx * cx;
            float kv = kx2[d >> 1][d & 1] * row[d];
            skv += kv;
            sdkv = fmaf(dx, kv, sdkv);
        }
        wd = fmaf(ky2[j][0], fmaf(dy, skv, sdkv), wd);
    }
    wd *= ureg;
    wd = blk_sum(wd, red);

    if (tid == 0) {
        parts[img * 3 + 0] = loss;
        parts[img * 3 + 1] = wd;
        parts[img * 3 + 2] = ot;
    }
}

__global__ void ot_sum(const float* __restrict__ parts, float* __restrict__ out)
{
    int t = threadIdx.x;
    if (t < 3) {
        float s = 0.f;
        for (int i = 0; i < N_IMG; ++i) s += parts[i * 3 + t];
        out[t] = s;
    }
}

// ---------------------------------------------------------------- launch ---
extern "C" void kernel_launch(void* const* d_in, const int* in_sizes, int n_in,
                              void* d_out, int out_size, void* d_ws, size_t ws_size,
                              hipStream_t stream_)
{
    const float* nd  = (const float*)d_in[0];   // normed_density  [8][16384]
    const float* und = (const float*)d_in[1];   // unnormed_density[8][16384]
    const float* pts = (const float*)d_in[2];   // points          [8][1024][2]

    char* ws = (char*)d_ws;
    uint4*  cstream = (uint4*)ws;                         // 8*32768*16 = 4MB
    u16*    pstream = (u16*)(ws + 4194304);               // 512KB
    u16*    tileofg = (u16*)(ws + 4718592);               // 16KB
    uint_t* cbaseg  = (uint_t*)(ws + 4734976);            // 512B
    uint_t* cleng   = (uint_t*)(ws + 4735488);            // 512B
    float*  parts   = (float*)(ws + 4736000);             // 96B
    // total < 5MB

    hipMemsetAsync(cstream, 0, 4194304, stream_);         // zero coeff pads
    ot_build<<<N_IMG, 1024, 0, stream_>>>(pts, cstream, pstream, tileofg, cbaseg, cleng);
    ot_fused<<<N_IMG, 1024, 0, stream_>>>(nd, und, pts, cstream, pstream, tileofg,
                                          cbaseg, cleng, parts);
    ot_sum<<<1, 64, 0, stream_>>>(parts, (float*)d_out);
}